// Round 1
// 1068.546 us; speedup vs baseline: 1.0110x; 1.0110x over previous
//
#include <hip/hip_runtime.h>

#define E_EDGES 1000000
#define N_NODES 100000
#define HID 128

// ---- workspace layout (bytes) ----
// 0    : counts[8]  (int)   -- per-combo edge counts (memset 0)
// 32   : cursor[8]  (int)   -- scatter cursors       (memset 0)
// 64   : seg[8]     (int)   -- padded segment starts (edges)
// 96   : tile[8]    (int)   -- segment starts in 64-edge tiles; tile[6]=total
// 256  : cmb[E]     (int8)  -- combo id per edge (-1 invalid)
// WS_LIST : list[E + 6*64] (int) -- bucketed edge ids, pad slots = -1 (memset 0xFF)
// WS_W1F  : w1 bf16 frags  6*12*8*64*8
// WS_W2F  : w2 bf16 frags  6*4*8*64*8
static constexpr int    WS_CMB  = 256;
static constexpr int    WS_LIST = 1000448;
static constexpr int    WS_W1F  = 5001984;   // 1000448 + 1000384*4 = 5001984 (256-aligned)
static constexpr int    WS_W2F  = 5591808;   // + 294912*2
// end = 5788416 bytes (~5.8 MB)

typedef __bf16 bf16x8 __attribute__((ext_vector_type(8)));
typedef float  f32x4  __attribute__((ext_vector_type(4)));

__device__ __forceinline__ unsigned short f2bf(float f) {
    unsigned int u = __builtin_bit_cast(unsigned int, f);
    u = (u + 0x7FFFu + ((u >> 16) & 1u)) >> 16;   // RNE
    return (unsigned short)u;
}

// ---------------- weight conversion: fp32 -> bf16 MFMA B-frag layout ----------------
// w1f flat idx: ((c*12+kt)*8+nt)*64*8 + lane*8 + j  ; element = W[k=kt*32+(lane>>4)*8+j][n=nt*16+(lane&15)]
__global__ void k_wconv(const float* __restrict__ W1, const float* __restrict__ W2,
                        unsigned short* __restrict__ w1f, unsigned short* __restrict__ w2f) {
    int idx = blockIdx.x * 256 + threadIdx.x;
    if (idx < 294912) {
        int j = idx & 7, lane = (idx >> 3) & 63, nt = (idx >> 9) & 7;
        int t = idx >> 12;            // 0..71
        int c = t / 12, kt = t - c * 12;
        int k = kt * 32 + ((lane >> 4) << 3) + j;
        int n = (nt << 4) + (lane & 15);
        w1f[idx] = f2bf(W1[(c * 384 + k) * 128 + n]);
    } else {
        int i2 = idx - 294912;        // < 98304
        int j = i2 & 7, lane = (i2 >> 3) & 63, nt = (i2 >> 9) & 7;
        int t = i2 >> 12;             // 0..23
        int c = t >> 2, kt = t & 3;
        int k = kt * 32 + ((lane >> 4) << 3) + j;
        int n = (nt << 4) + (lane & 15);
        w2f[i2] = f2bf(W2[(c * 128 + k) * 128 + n]);
    }
}

// ---------------- classify edges, count per combo, zero invalid outputs ----------------
__global__ void k_classify(const int* __restrict__ ei, const int* __restrict__ vol,
                           signed char* __restrict__ cmb, float* __restrict__ out,
                           int* __restrict__ counts) {
    __shared__ int bc[6];
    int tid = threadIdx.x;
    if (tid < 6) bc[tid] = 0;
    __syncthreads();
    int eid = blockIdx.x * 256 + tid;
    if (eid < E_EDGES) {
        int s = ei[eid], t = ei[E_EDGES + eid];
        int gs = vol[s] / 3, ge = vol[t] / 3;     // volume 0..8 -> group 0..2
        int cc = -1;
        if (gs <= ge) cc = (gs == 0 ? 0 : (gs == 1 ? 2 : 3)) + ge;  // (0,0)(0,1)(0,2)(1,1)(1,2)(2,2)
        cmb[eid] = (signed char)cc;
        if (cc < 0) out[eid] = 0.f;
        else atomicAdd(&bc[cc], 1);
    }
    __syncthreads();
    if (tid < 6 && bc[tid] > 0) atomicAdd(&counts[tid], bc[tid]);
}

// ---------------- segment offsets (pad each combo to multiple of 64) ----------------
__global__ void k_offsets(int* __restrict__ ws) {
    if (threadIdx.x == 0 && blockIdx.x == 0) {
        int* counts = ws;        // ints 0..7
        int* seg    = ws + 16;   // byte 64
        int* tile   = ws + 24;   // byte 96
        int acc = 0;
        for (int c = 0; c < 6; ++c) {
            seg[c]  = acc;
            tile[c] = acc >> 6;
            acc += ((counts[c] + 63) >> 6) << 6;
        }
        seg[6]  = acc;
        tile[6] = acc >> 6;      // total tiles
    }
}

// ---------------- scatter edge ids into combo buckets ----------------
__global__ void k_scatter(const signed char* __restrict__ cmb, int* __restrict__ list,
                          const int* __restrict__ seg, int* __restrict__ cursor) {
    __shared__ int bc[6], basep[6];
    int tid = threadIdx.x;
    if (tid < 6) bc[tid] = 0;
    __syncthreads();
    int eid = blockIdx.x * 256 + tid;
    int cc = -1, lp = 0;
    if (eid < E_EDGES) {
        cc = cmb[eid];
        if (cc >= 0) lp = atomicAdd(&bc[cc], 1);
    }
    __syncthreads();
    if (tid < 6) basep[tid] = bc[tid] > 0 ? atomicAdd(&cursor[tid], bc[tid]) : 0;
    __syncthreads();
    if (cc >= 0) list[seg[cc] + basep[cc] + lp] = eid;
}

// ---------------- fused MLP over one 64-edge tile of one combo ----------------
// v2: NO block-wide A staging, NO __syncthreads. Each wave owns one 16-row M-tile;
// A-fragments (8 consecutive floats of [xs|xe|e]) are gathered straight from global
// into registers and converted in-reg. LDS holds only the per-wave h1 transpose
// buffer (16 rows x stride 136 bf16, 4352 B/wave = 17408 B/block -> ~8 blocks/CU LDS-wise).
__global__ __launch_bounds__(256) void k_mlp(
    const float* __restrict__ x, const int* __restrict__ ei, const float* __restrict__ efeat,
    const int* __restrict__ tile_tab, const int* __restrict__ list,
    const unsigned short* __restrict__ w1f, const unsigned short* __restrict__ w2f,
    const float* __restrict__ b1, const float* __restrict__ g1, const float* __restrict__ be1,
    const float* __restrict__ b2, const float* __restrict__ g2, const float* __restrict__ be2,
    const float* __restrict__ W3, const float* __restrict__ b3,
    float* __restrict__ out)
{
    __shared__ unsigned short H1[4 * 16 * 136];   // per-wave private h1 regions

    int b = blockIdx.x;
    if (b >= tile_tab[6]) return;
    int c = 0;
#pragma unroll
    for (int k = 1; k < 6; ++k) if (b >= tile_tab[k]) c = k;
    int tb = b - tile_tab[c];
    int segbase = tile_tab[c] * 64;

    int tid  = threadIdx.x;
    int lane = tid & 63;
    int wv   = tid >> 6;          // wave = one 16-row M-tile
    int colb = lane & 15;
    int quad = lane >> 4;

    // lane (quad,colb) supplies A data for edge row `colb` of this wave's tile
    int eid  = list[segbase + tb * 64 + wv * 16 + colb];
    int eidS = eid >= 0 ? eid : 0;            // safe index: invalid rows read real
    int s = ei[eidS], t = ei[E_EDGES + eidS]; // (finite) data, output is eid-guarded

    const float* xs = x + (long)s * 128;
    const float* xe = x + (long)t * 128;
    const float* ee = efeat + (long)eidS * 128;

    const bf16x8* w1v = (const bf16x8*)w1f;
    const bf16x8* w2v = (const bf16x8*)w2f;
    const f32x4 zero4 = {0.f, 0.f, 0.f, 0.f};

    // ---- layer 1: [64x384] @ [384x128], A gathered per-lane from global ----
    f32x4 acc[8];
#pragma unroll
    for (int nt = 0; nt < 8; ++nt) acc[nt] = zero4;
    int koff = quad * 8;
#pragma unroll
    for (int kt = 0; kt < 12; ++kt) {
        const float* src = (kt < 4) ? xs : ((kt < 8) ? xe : ee);
        int o = (kt & 3) * 32 + koff;
        float4 v0 = *(const float4*)(src + o);
        float4 v1 = *(const float4*)(src + o + 4);
        bf16x8 af;
        af[0] = (__bf16)v0.x; af[1] = (__bf16)v0.y; af[2] = (__bf16)v0.z; af[3] = (__bf16)v0.w;
        af[4] = (__bf16)v1.x; af[5] = (__bf16)v1.y; af[6] = (__bf16)v1.z; af[7] = (__bf16)v1.w;
        int wbase = ((c * 12 + kt) * 8) * 64 + lane;
#pragma unroll
        for (int nt = 0; nt < 8; ++nt) {
            bf16x8 bfr = w1v[wbase + nt * 64];
            acc[nt] = __builtin_amdgcn_mfma_f32_16x16x32_bf16(af, bfr, acc[nt], 0, 0, 0);
        }
    }

    // ---- LN1 + relu (in-register; C row = quad*4+reg, col = colb+nt*16) ----
    float pb[8], pg[8], pe[8];
#pragma unroll
    for (int nt = 0; nt < 8; ++nt) {
        int col = c * 128 + colb + nt * 16;
        pb[nt] = b1[col]; pg[nt] = g1[col]; pe[nt] = be1[col];
    }
    float sum[4] = {0, 0, 0, 0}, sq[4] = {0, 0, 0, 0};
#pragma unroll
    for (int nt = 0; nt < 8; ++nt)
#pragma unroll
        for (int r = 0; r < 4; ++r) {
            float v = acc[nt][r] + pb[nt];
            acc[nt][r] = v;
            sum[r] += v; sq[r] += v * v;
        }
#pragma unroll
    for (int m = 1; m < 16; m <<= 1)
#pragma unroll
        for (int r = 0; r < 4; ++r) {
            sum[r] += __shfl_xor(sum[r], m);
            sq[r]  += __shfl_xor(sq[r], m);
        }
    float mean_[4], rstd_[4];
#pragma unroll
    for (int r = 0; r < 4; ++r) {
        float mu = sum[r] * 0.0078125f;
        float var = sq[r] * 0.0078125f - mu * mu;
        mean_[r] = mu;
        rstd_[r] = rsqrtf(var + 1e-5f);
    }
    // write h1 (bf16) into this wave's private LDS region, row-major stride 136
    int h1base = wv * 2176;
#pragma unroll
    for (int nt = 0; nt < 8; ++nt)
#pragma unroll
        for (int r = 0; r < 4; ++r) {
            float v = (acc[nt][r] - mean_[r]) * rstd_[r] * pg[nt] + pe[nt];
            v = fmaxf(v, 0.f);
            H1[h1base + (quad * 4 + r) * 136 + colb + nt * 16] =
                __builtin_bit_cast(unsigned short, (__bf16)v);
        }

    // ---- layer 2: [16x128] @ [128x128] (per wave; same-wave LDS RAW, program order) ----
    f32x4 acc2[8];
#pragma unroll
    for (int nt = 0; nt < 8; ++nt) acc2[nt] = zero4;
    int h1row = wv * 2176 + colb * 136 + quad * 8;
#pragma unroll
    for (int kt = 0; kt < 4; ++kt) {
        bf16x8 af = *(const bf16x8*)(&H1[h1row + kt * 32]);
        int wbase = ((c * 4 + kt) * 8) * 64 + lane;
#pragma unroll
        for (int nt = 0; nt < 8; ++nt) {
            bf16x8 bfr = w2v[wbase + nt * 64];
            acc2[nt] = __builtin_amdgcn_mfma_f32_16x16x32_bf16(af, bfr, acc2[nt], 0, 0, 0);
        }
    }

    // ---- LN2 + relu fused with layer 3 dot (h2 . W3) ----
#pragma unroll
    for (int nt = 0; nt < 8; ++nt) {
        int col = c * 128 + colb + nt * 16;
        pb[nt] = b2[col]; pg[nt] = g2[col]; pe[nt] = be2[col];
    }
#pragma unroll
    for (int r = 0; r < 4; ++r) { sum[r] = 0.f; sq[r] = 0.f; }
#pragma unroll
    for (int nt = 0; nt < 8; ++nt)
#pragma unroll
        for (int r = 0; r < 4; ++r) {
            float v = acc2[nt][r] + pb[nt];
            acc2[nt][r] = v;
            sum[r] += v; sq[r] += v * v;
        }
#pragma unroll
    for (int m = 1; m < 16; m <<= 1)
#pragma unroll
        for (int r = 0; r < 4; ++r) {
            sum[r] += __shfl_xor(sum[r], m);
            sq[r]  += __shfl_xor(sq[r], m);
        }
#pragma unroll
    for (int r = 0; r < 4; ++r) {
        float mu = sum[r] * 0.0078125f;
        float var = sq[r] * 0.0078125f - mu * mu;
        mean_[r] = mu;
        rstd_[r] = rsqrtf(var + 1e-5f);
    }
    float w3v[8];
#pragma unroll
    for (int nt = 0; nt < 8; ++nt) w3v[nt] = W3[c * 128 + colb + nt * 16];
    float part[4] = {0, 0, 0, 0};
#pragma unroll
    for (int nt = 0; nt < 8; ++nt)
#pragma unroll
        for (int r = 0; r < 4; ++r) {
            float v = (acc2[nt][r] - mean_[r]) * rstd_[r] * pg[nt] + pe[nt];
            v = fmaxf(v, 0.f);
            part[r] += v * w3v[nt];
        }
#pragma unroll
    for (int m = 1; m < 16; m <<= 1)
#pragma unroll
        for (int r = 0; r < 4; ++r) part[r] += __shfl_xor(part[r], m);

    float b3v = b3[c];
#pragma unroll
    for (int r = 0; r < 4; ++r) {
        int esel = __shfl(eid, quad * 4 + r);   // eid of C-row quad*4+r (lane colb==row holds it)
        if (colb == 0 && esel >= 0) out[esel] = part[r] + b3v;
    }
}

extern "C" void kernel_launch(void* const* d_in, const int* in_sizes, int n_in,
                              void* d_out, int out_size, void* d_ws, size_t ws_size,
                              hipStream_t stream) {
    const float* x    = (const float*)d_in[0];
    const int*   ei   = (const int*)d_in[1];
    const float* e    = (const float*)d_in[2];
    const int*   vol  = (const int*)d_in[3];
    const float* W1   = (const float*)d_in[4];
    const float* b1   = (const float*)d_in[5];
    const float* g1   = (const float*)d_in[6];
    const float* be1  = (const float*)d_in[7];
    const float* W2   = (const float*)d_in[8];
    const float* b2   = (const float*)d_in[9];
    const float* g2   = (const float*)d_in[10];
    const float* be2  = (const float*)d_in[11];
    const float* W3   = (const float*)d_in[12];
    const float* b3   = (const float*)d_in[13];
    float* out = (float*)d_out;
    char* wsb = (char*)d_ws;

    hipMemsetAsync(wsb, 0, 256, stream);                                     // counters/cursors
    hipMemsetAsync(wsb + WS_LIST, 0xFF, (E_EDGES + 384) * sizeof(int), stream); // pad slots = -1

    k_wconv<<<1536, 256, 0, stream>>>(W1, W2,
        (unsigned short*)(wsb + WS_W1F), (unsigned short*)(wsb + WS_W2F));
    k_classify<<<(E_EDGES + 255) / 256, 256, 0, stream>>>(ei, vol,
        (signed char*)(wsb + WS_CMB), out, (int*)wsb);
    k_offsets<<<1, 64, 0, stream>>>((int*)wsb);
    k_scatter<<<(E_EDGES + 255) / 256, 256, 0, stream>>>(
        (const signed char*)(wsb + WS_CMB), (int*)(wsb + WS_LIST),
        (const int*)(wsb + 64), (int*)(wsb + 32));
    k_mlp<<<E_EDGES / 64 + 6, 256, 0, stream>>>(
        x, ei, e, (const int*)(wsb + 96), (const int*)(wsb + WS_LIST),
        (const unsigned short*)(wsb + WS_W1F), (const unsigned short*)(wsb + WS_W2F),
        b1, g1, be1, b2, g2, be2, W3, b3, out);
}

// Round 2
// 1049.677 us; speedup vs baseline: 1.0291x; 1.0180x over previous
//
#include <hip/hip_runtime.h>

#define E_EDGES 1000000
#define N_NODES 100000
#define HID 128

// ---- workspace layout (bytes) ----
// 0    : seg[8]            (int)  -- padded combo segment starts (edge slots); seg[6]=total
// 64   : counts2D[6][32]   (int)  -- per-combo, per-slice edge counts (memset 0)
// 832  : cursor2D[6][32]   (int)  -- scatter cursors, init to slice bases by k_offsets
// 1600 : cmb[E]            (int8) -- combo id per edge (-1 invalid)
// WS_LIST : list[E + 384] (int)   -- bucketed edge ids, pad slots = -1 (memset 0xFF)
// WS_W1F  : w1 bf16 frags  6*12*8*64*8 ushorts
// WS_W2F  : w2 bf16 frags  6*4*8*64*8 ushorts
static constexpr int    WS_CMB  = 1600;
static constexpr int    WS_LIST = 1001664;   // 64-aligned
static constexpr int    WS_W1F  = 5003264;   // WS_LIST + (E+384)*4 = 5003200, 256-aligned up
static constexpr int    WS_W2F  = 5593088;   // + 589824
// end = 5789696 bytes (~5.8 MB)

typedef __bf16 bf16x8 __attribute__((ext_vector_type(8)));
typedef float  f32x4  __attribute__((ext_vector_type(4)));

__device__ __forceinline__ unsigned short f2bf(float f) {
    unsigned int u = __builtin_bit_cast(unsigned int, f);
    u = (u + 0x7FFFu + ((u >> 16) & 1u)) >> 16;   // RNE
    return (unsigned short)u;
}

// ---------------- weight conversion: fp32 -> bf16 MFMA B-frag layout ----------------
// w1f flat idx: ((c*12+kt)*8+nt)*64*8 + lane*8 + j  ; element = W[k=kt*32+(lane>>4)*8+j][n=nt*16+(lane&15)]
__global__ void k_wconv(const float* __restrict__ W1, const float* __restrict__ W2,
                        unsigned short* __restrict__ w1f, unsigned short* __restrict__ w2f) {
    int idx = blockIdx.x * 256 + threadIdx.x;
    if (idx < 294912) {
        int j = idx & 7, lane = (idx >> 3) & 63, nt = (idx >> 9) & 7;
        int t = idx >> 12;            // 0..71
        int c = t / 12, kt = t - c * 12;
        int k = kt * 32 + ((lane >> 4) << 3) + j;
        int n = (nt << 4) + (lane & 15);
        w1f[idx] = f2bf(W1[(c * 384 + k) * 128 + n]);
    } else {
        int i2 = idx - 294912;        // < 98304
        int j = i2 & 7, lane = (i2 >> 3) & 63, nt = (i2 >> 9) & 7;
        int t = i2 >> 12;             // 0..23
        int c = t >> 2, kt = t & 3;
        int k = kt * 32 + ((lane >> 4) << 3) + j;
        int n = (nt << 4) + (lane & 15);
        w2f[i2] = f2bf(W2[(c * 128 + k) * 128 + n]);
    }
}

// ---------------- classify edges, count per (combo, slice), zero invalid outputs ----------------
__global__ void k_classify(const int* __restrict__ ei, const int* __restrict__ vol,
                           signed char* __restrict__ cmb, float* __restrict__ out,
                           int* __restrict__ counts2D) {
    __shared__ int bc[6];
    int tid = threadIdx.x;
    if (tid < 6) bc[tid] = 0;
    __syncthreads();
    int eid = blockIdx.x * 256 + tid;
    if (eid < E_EDGES) {
        int s = ei[eid], t = ei[E_EDGES + eid];
        int gs = vol[s] / 3, ge = vol[t] / 3;     // volume 0..8 -> group 0..2
        int cc = -1;
        if (gs <= ge) cc = (gs == 0 ? 0 : (gs == 1 ? 2 : 3)) + ge;  // (0,0)(0,1)(0,2)(1,1)(1,2)(2,2)
        cmb[eid] = (signed char)cc;
        if (cc < 0) out[eid] = 0.f;
        else atomicAdd(&bc[cc], 1);
    }
    __syncthreads();
    // 32-way sliced counters: contention per address /32
    if (tid < 6 && bc[tid] > 0)
        atomicAdd(&counts2D[tid * 32 + (blockIdx.x & 31)], bc[tid]);
}

// ---------------- segment offsets + per-slice scatter bases ----------------
__global__ void k_offsets(int* __restrict__ ws) {
    __shared__ int cnt[192], base[192], segs[8];
    int tid = threadIdx.x;
    if (tid < 192) cnt[tid] = ws[16 + tid];         // counts2D at int offset 16
    __syncthreads();
    if (tid == 0) {
        int acc = 0;
        for (int c = 0; c < 6; ++c) {
            segs[c] = acc;
            int tot = 0;
            for (int s = 0; s < 32; ++s) { base[c * 32 + s] = acc + tot; tot += cnt[c * 32 + s]; }
            acc += ((tot + 63) >> 6) << 6;          // pad combo to multiple of 64
        }
        segs[6] = acc; segs[7] = 0;
    }
    __syncthreads();
    if (tid < 192) ws[208 + tid] = base[tid];       // cursor2D at int offset 208 (absolute bases)
    if (tid < 8)   ws[tid] = segs[tid];             // seg at int offset 0
}

// ---------------- scatter edge ids into combo buckets (sliced cursors, no hot atomics) ----------------
__global__ void k_scatter(const signed char* __restrict__ cmb, int* __restrict__ list,
                          int* __restrict__ cursor2D) {
    __shared__ int bc[6], basep[6];
    int tid = threadIdx.x;
    if (tid < 6) bc[tid] = 0;
    __syncthreads();
    int eid = blockIdx.x * 256 + tid;
    int cc = -1, lp = 0;
    if (eid < E_EDGES) {
        cc = cmb[eid];
        if (cc >= 0) lp = atomicAdd(&bc[cc], 1);
    }
    __syncthreads();
    if (tid < 6) basep[tid] = bc[tid] > 0
        ? atomicAdd(&cursor2D[tid * 32 + (blockIdx.x & 31)], bc[tid]) : 0;
    __syncthreads();
    if (cc >= 0) list[basep[cc] + lp] = eid;        // bases are absolute slot indices
}

// ---------------- fused MLP; each wave owns a 32-row chunk (two 16-row C-tiles) ----------------
// B-fragments feed TWO MFMAs each (halves weight L2 traffic per edge, 2x MFMA ILP).
// No __syncthreads anywhere; LDS = per-wave h1 transpose buffer only.
__global__ __launch_bounds__(256, 4) void k_mlp(
    const float* __restrict__ x, const int* __restrict__ ei, const float* __restrict__ efeat,
    const int* __restrict__ seg, const int* __restrict__ list,
    const unsigned short* __restrict__ w1f, const unsigned short* __restrict__ w2f,
    const float* __restrict__ b1, const float* __restrict__ g1, const float* __restrict__ be1,
    const float* __restrict__ b2, const float* __restrict__ g2, const float* __restrict__ be2,
    const float* __restrict__ W3, const float* __restrict__ b3,
    float* __restrict__ out)
{
    __shared__ unsigned short H1[4 * 32 * 136];   // 4 waves x 32 rows x stride 136

    int tid  = threadIdx.x;
    int lane = tid & 63;
    int wv   = tid >> 6;
    int p    = blockIdx.x * 128 + wv * 32;        // this wave's 32-slot chunk
    if (p >= seg[6]) return;                      // no barriers in kernel: per-wave exit OK
    int c = 0;
#pragma unroll
    for (int k = 1; k < 6; ++k) if (p >= seg[k]) c = k;   // 32-chunk never straddles (seg 64-aligned)

    int colb = lane & 15;
    int quad = lane >> 4;

    // lane supplies A-rows colb (tile 0) and 16+colb (tile 1)
    int eid0 = list[p + colb];
    int eid1 = list[p + 16 + colb];
    int e0S = eid0 >= 0 ? eid0 : 0;
    int e1S = eid1 >= 0 ? eid1 : 0;
    int s0 = ei[e0S], t0 = ei[E_EDGES + e0S];
    int s1 = ei[e1S], t1 = ei[E_EDGES + e1S];

    const float* xs0 = x + (long)s0 * 128;
    const float* xe0 = x + (long)t0 * 128;
    const float* ee0 = efeat + (long)e0S * 128;
    const float* xs1 = x + (long)s1 * 128;
    const float* xe1 = x + (long)t1 * 128;
    const float* ee1 = efeat + (long)e1S * 128;

    const bf16x8* w1v = (const bf16x8*)w1f;
    const bf16x8* w2v = (const bf16x8*)w2f;
    const f32x4 zero4 = {0.f, 0.f, 0.f, 0.f};

    // ---- layer 1: [32x384] @ [384x128] per wave ----
    f32x4 acc0[8], acc1[8];
#pragma unroll
    for (int nt = 0; nt < 8; ++nt) { acc0[nt] = zero4; acc1[nt] = zero4; }
    int koff = quad * 8;
#pragma unroll
    for (int kt = 0; kt < 12; ++kt) {
        const float* p0 = (kt < 4) ? xs0 : ((kt < 8) ? xe0 : ee0);
        const float* p1 = (kt < 4) ? xs1 : ((kt < 8) ? xe1 : ee1);
        int o = (kt & 3) * 32 + koff;
        float4 va0 = *(const float4*)(p0 + o);
        float4 va1 = *(const float4*)(p0 + o + 4);
        float4 vb0 = *(const float4*)(p1 + o);
        float4 vb1 = *(const float4*)(p1 + o + 4);
        bf16x8 af0, af1;
        af0[0] = (__bf16)va0.x; af0[1] = (__bf16)va0.y; af0[2] = (__bf16)va0.z; af0[3] = (__bf16)va0.w;
        af0[4] = (__bf16)va1.x; af0[5] = (__bf16)va1.y; af0[6] = (__bf16)va1.z; af0[7] = (__bf16)va1.w;
        af1[0] = (__bf16)vb0.x; af1[1] = (__bf16)vb0.y; af1[2] = (__bf16)vb0.z; af1[3] = (__bf16)vb0.w;
        af1[4] = (__bf16)vb1.x; af1[5] = (__bf16)vb1.y; af1[6] = (__bf16)vb1.z; af1[7] = (__bf16)vb1.w;
        int wb = ((c * 12 + kt) * 8) * 64 + lane;
#pragma unroll
        for (int nt = 0; nt < 8; ++nt) {
            bf16x8 bfr = w1v[wb + nt * 64];
            acc0[nt] = __builtin_amdgcn_mfma_f32_16x16x32_bf16(af0, bfr, acc0[nt], 0, 0, 0);
            acc1[nt] = __builtin_amdgcn_mfma_f32_16x16x32_bf16(af1, bfr, acc1[nt], 0, 0, 0);
        }
    }

    // ---- LN1 + relu (C row = quad*4+r, col = colb+nt*16) ----
    float pb[8], pg[8], pe[8];
#pragma unroll
    for (int nt = 0; nt < 8; ++nt) {
        int col = c * 128 + colb + nt * 16;
        pb[nt] = b1[col]; pg[nt] = g1[col]; pe[nt] = be1[col];
    }
    float s0a[4] = {0,0,0,0}, q0a[4] = {0,0,0,0}, s1a[4] = {0,0,0,0}, q1a[4] = {0,0,0,0};
#pragma unroll
    for (int nt = 0; nt < 8; ++nt)
#pragma unroll
        for (int r = 0; r < 4; ++r) {
            float v = acc0[nt][r] + pb[nt];
            acc0[nt][r] = v; s0a[r] += v; q0a[r] += v * v;
            float w = acc1[nt][r] + pb[nt];
            acc1[nt][r] = w; s1a[r] += w; q1a[r] += w * w;
        }
#pragma unroll
    for (int m = 1; m < 16; m <<= 1)
#pragma unroll
        for (int r = 0; r < 4; ++r) {
            s0a[r] += __shfl_xor(s0a[r], m); q0a[r] += __shfl_xor(q0a[r], m);
            s1a[r] += __shfl_xor(s1a[r], m); q1a[r] += __shfl_xor(q1a[r], m);
        }
    float mean0[4], rstd0[4], mean1[4], rstd1[4];
#pragma unroll
    for (int r = 0; r < 4; ++r) {
        float mu0 = s0a[r] * 0.0078125f, mu1 = s1a[r] * 0.0078125f;
        mean0[r] = mu0; rstd0[r] = rsqrtf(q0a[r] * 0.0078125f - mu0 * mu0 + 1e-5f);
        mean1[r] = mu1; rstd1[r] = rsqrtf(q1a[r] * 0.0078125f - mu1 * mu1 + 1e-5f);
    }
    int h1base = wv * 4352;
#pragma unroll
    for (int nt = 0; nt < 8; ++nt)
#pragma unroll
        for (int r = 0; r < 4; ++r) {
            float v = (acc0[nt][r] - mean0[r]) * rstd0[r] * pg[nt] + pe[nt];
            v = fmaxf(v, 0.f);
            H1[h1base + (quad * 4 + r) * 136 + colb + nt * 16] =
                __builtin_bit_cast(unsigned short, (__bf16)v);
            float w = (acc1[nt][r] - mean1[r]) * rstd1[r] * pg[nt] + pe[nt];
            w = fmaxf(w, 0.f);
            H1[h1base + (16 + quad * 4 + r) * 136 + colb + nt * 16] =
                __builtin_bit_cast(unsigned short, (__bf16)w);
        }

    // ---- layer 2: [32x128] @ [128x128] (same-wave LDS RAW, program order) ----
    f32x4 acc20[8], acc21[8];
#pragma unroll
    for (int nt = 0; nt < 8; ++nt) { acc20[nt] = zero4; acc21[nt] = zero4; }
    int h1r0 = h1base + colb * 136 + quad * 8;
    int h1r1 = h1r0 + 16 * 136;
#pragma unroll
    for (int kt = 0; kt < 4; ++kt) {
        bf16x8 af0 = *(const bf16x8*)(&H1[h1r0 + kt * 32]);
        bf16x8 af1 = *(const bf16x8*)(&H1[h1r1 + kt * 32]);
        int wb = ((c * 4 + kt) * 8) * 64 + lane;
#pragma unroll
        for (int nt = 0; nt < 8; ++nt) {
            bf16x8 bfr = w2v[wb + nt * 64];
            acc20[nt] = __builtin_amdgcn_mfma_f32_16x16x32_bf16(af0, bfr, acc20[nt], 0, 0, 0);
            acc21[nt] = __builtin_amdgcn_mfma_f32_16x16x32_bf16(af1, bfr, acc21[nt], 0, 0, 0);
        }
    }

    // ---- LN2 + relu fused with layer 3 dot (h2 . W3) ----
#pragma unroll
    for (int nt = 0; nt < 8; ++nt) {
        int col = c * 128 + colb + nt * 16;
        pb[nt] = b2[col]; pg[nt] = g2[col]; pe[nt] = be2[col];
    }
#pragma unroll
    for (int r = 0; r < 4; ++r) { s0a[r] = 0.f; q0a[r] = 0.f; s1a[r] = 0.f; q1a[r] = 0.f; }
#pragma unroll
    for (int nt = 0; nt < 8; ++nt)
#pragma unroll
        for (int r = 0; r < 4; ++r) {
            float v = acc20[nt][r] + pb[nt];
            acc20[nt][r] = v; s0a[r] += v; q0a[r] += v * v;
            float w = acc21[nt][r] + pb[nt];
            acc21[nt][r] = w; s1a[r] += w; q1a[r] += w * w;
        }
#pragma unroll
    for (int m = 1; m < 16; m <<= 1)
#pragma unroll
        for (int r = 0; r < 4; ++r) {
            s0a[r] += __shfl_xor(s0a[r], m); q0a[r] += __shfl_xor(q0a[r], m);
            s1a[r] += __shfl_xor(s1a[r], m); q1a[r] += __shfl_xor(q1a[r], m);
        }
#pragma unroll
    for (int r = 0; r < 4; ++r) {
        float mu0 = s0a[r] * 0.0078125f, mu1 = s1a[r] * 0.0078125f;
        mean0[r] = mu0; rstd0[r] = rsqrtf(q0a[r] * 0.0078125f - mu0 * mu0 + 1e-5f);
        mean1[r] = mu1; rstd1[r] = rsqrtf(q1a[r] * 0.0078125f - mu1 * mu1 + 1e-5f);
    }
    float w3v[8];
#pragma unroll
    for (int nt = 0; nt < 8; ++nt) w3v[nt] = W3[c * 128 + colb + nt * 16];
    float part0[4] = {0,0,0,0}, part1[4] = {0,0,0,0};
#pragma unroll
    for (int nt = 0; nt < 8; ++nt)
#pragma unroll
        for (int r = 0; r < 4; ++r) {
            float v = (acc20[nt][r] - mean0[r]) * rstd0[r] * pg[nt] + pe[nt];
            part0[r] += fmaxf(v, 0.f) * w3v[nt];
            float w = (acc21[nt][r] - mean1[r]) * rstd1[r] * pg[nt] + pe[nt];
            part1[r] += fmaxf(w, 0.f) * w3v[nt];
        }
#pragma unroll
    for (int m = 1; m < 16; m <<= 1)
#pragma unroll
        for (int r = 0; r < 4; ++r) {
            part0[r] += __shfl_xor(part0[r], m);
            part1[r] += __shfl_xor(part1[r], m);
        }

    float b3v = b3[c];
#pragma unroll
    for (int r = 0; r < 4; ++r) {
        int es0 = __shfl(eid0, quad * 4 + r);    // eid of tile-0 row quad*4+r (held by lane colb==row)
        int es1 = __shfl(eid1, quad * 4 + r);
        if (colb == 0 && es0 >= 0) out[es0] = part0[r] + b3v;
        if (colb == 0 && es1 >= 0) out[es1] = part1[r] + b3v;
    }
}

extern "C" void kernel_launch(void* const* d_in, const int* in_sizes, int n_in,
                              void* d_out, int out_size, void* d_ws, size_t ws_size,
                              hipStream_t stream) {
    const float* x    = (const float*)d_in[0];
    const int*   ei   = (const int*)d_in[1];
    const float* e    = (const float*)d_in[2];
    const int*   vol  = (const int*)d_in[3];
    const float* W1   = (const float*)d_in[4];
    const float* b1   = (const float*)d_in[5];
    const float* g1   = (const float*)d_in[6];
    const float* be1  = (const float*)d_in[7];
    const float* W2   = (const float*)d_in[8];
    const float* b2   = (const float*)d_in[9];
    const float* g2   = (const float*)d_in[10];
    const float* be2  = (const float*)d_in[11];
    const float* W3   = (const float*)d_in[12];
    const float* b3   = (const float*)d_in[13];
    float* out = (float*)d_out;
    char* wsb = (char*)d_ws;

    hipMemsetAsync(wsb, 0, 1600, stream);                                       // seg+counts2D+cursor2D
    hipMemsetAsync(wsb + WS_LIST, 0xFF, (E_EDGES + 384) * sizeof(int), stream); // pad slots = -1

    k_wconv<<<1536, 256, 0, stream>>>(W1, W2,
        (unsigned short*)(wsb + WS_W1F), (unsigned short*)(wsb + WS_W2F));
    k_classify<<<(E_EDGES + 255) / 256, 256, 0, stream>>>(ei, vol,
        (signed char*)(wsb + WS_CMB), out, (int*)(wsb + 64));
    k_offsets<<<1, 256, 0, stream>>>((int*)wsb);
    k_scatter<<<(E_EDGES + 255) / 256, 256, 0, stream>>>(
        (const signed char*)(wsb + WS_CMB), (int*)(wsb + WS_LIST),
        (int*)(wsb + 832));
    k_mlp<<<E_EDGES / 128 + 6, 256, 0, stream>>>(
        x, ei, e, (const int*)wsb, (const int*)(wsb + WS_LIST),
        (const unsigned short*)(wsb + WS_W1F), (const unsigned short*)(wsb + WS_W2F),
        b1, g1, be1, b2, g2, be2, W3, b3, out);
}